// Round 15
// baseline (332.021 us; speedup 1.0000x reference)
//
#include <hip/hip_runtime.h>

// Problem constants (match reference setup_inputs)
#define NP 50000     // P: rows of HG_pu / rows of x,e,out
#define NU 100000    // U: rows of HG_up (intermediate y)
#define NNZ_C 1600000
#define NNZ2 (2 * NNZ_C)
#define DIM 128
#define NR_TOT (NU + NP)          // combined rows: [0,NU)=up, [NU,NU+NP)=pu

#define RBSH 7                    // rows per bucket = 128
#define RB 128
#define NBK ((NR_TOT + RB - 1) / RB)   // 1172 buckets
#define ITEMS 3072                // items per partition block (one chunk)
#define NBLK ((NNZ2 + ITEMS - 1) / ITEMS)  // 1042 partition blocks
#define CHUNK 3072
#define CPT (CHUNK / 256)         // 12 items per thread
#define CVT_NW (NP * 64)          // bf16x2 words in xh
#define CVT_BLKS ((CVT_NW + 255) / 256)   // 12500

// Fixed-capacity buckets
#define CAP_UP 2600
#define CAP_PU 4900
#define FPT 20                    // finalize items/thread bound: CAP_PU/256
#define NSLOT (1172 * CAP_UP + 391 * (CAP_PU - CAP_UP))   // 3,946,500
__device__ __host__ inline int bkt_base(int b) {
    return b * CAP_UP + (b > 781 ? (b - 781) * (CAP_PU - CAP_UP) : 0);
}

// finalize split: buckets [0,782) needed by gather-1 (incl. mixed 781);
// buckets [782,1172) needed only by gather-2 -> merged into gather-1 launch.
#define FINUP_NB 782
#define FINPU_NB (NBK - FINUP_NB)      // 390
#define G1_BLKS (NU / 4)               // 25000

// round-to-nearest bf16x2 pack: a -> low 16, b -> high 16
__device__ inline unsigned pack_bf16x2(float a, float b) {
    unsigned ia = __float_as_uint(a), ib = __float_as_uint(b);
    ia = (ia + 0x7FFFu + ((ia >> 16) & 1u)) >> 16;
    ib = (ib + 0x7FFFu + ((ib >> 16) & 1u)) >> 16;
    return ia | (ib << 16);
}

__device__ inline float dec_val(unsigned p) {
    return __uint_as_float((p & 0x7FFFu) << 16);   // exact bf16 -> f32
}

// ---------------------------------------------------------------------------
// Merged: x -> bf16 conversion  +  per-block bucket histogram.
// hist_all layout is [blk][bucket] -> COALESCED writes (r10 lesson:
// scattered sub-line WRITES pay full HBM granule; reads do not).
// ---------------------------------------------------------------------------
__global__ void cvt_hist_kernel(const float* __restrict__ x,
                                unsigned* __restrict__ xh,
                                const int* __restrict__ rows_up,
                                const int* __restrict__ rows_pu,
                                int* __restrict__ hist_all) {
    __shared__ int h[NBK];
    if (blockIdx.x < NBLK) {
        for (int k = threadIdx.x; k < NBK; k += 256) h[k] = 0;
        __syncthreads();
        int base = blockIdx.x * ITEMS;
        for (int k = 0; k < ITEMS / 256; ++k) {
            int i = base + k * 256 + threadIdx.x;
            if (i >= NNZ2) break;
            int r = (i < NNZ_C) ? rows_up[i] : (NU + rows_pu[i - NNZ_C]);
            atomicAdd(&h[r >> RBSH], 1);
        }
        __syncthreads();
        for (int k = threadIdx.x; k < NBK; k += 256)
            hist_all[blockIdx.x * NBK + k] = h[k];       // coalesced
    } else {
        int i = (blockIdx.x - NBLK) * 256 + threadIdx.x;
        if (i < CVT_NW) {
            float2 v = ((const float2*)x)[i];
            xh[i] = pack_bf16x2(v.x, v.y);
        }
    }
}

// ---------------------------------------------------------------------------
// Phase 1b: one block per bucket, exclusive scan over its NBLK counts.
// 512 thr x 3 elems = 1536 >= NBLK(1042). Strided reads benign; coalesced
// writes. Wave-shfl scan; 1 barrier.
// ---------------------------------------------------------------------------
__global__ void p1_scan_kernel(const int* __restrict__ hist_all,
                               int* __restrict__ base_all,
                               int* __restrict__ totals) {
    __shared__ int ws[8];
    int b = blockIdx.x;
    int tid = threadIdx.x;
    int t0 = tid * 3;
    int e0 = (t0 < NBLK) ? hist_all[t0 * NBK + b] : 0;          // strided read
    int e1 = (t0 + 1 < NBLK) ? hist_all[(t0 + 1) * NBK + b] : 0;
    int e2 = (t0 + 2 < NBLK) ? hist_all[(t0 + 2) * NBK + b] : 0;
    int a = e0 + e1 + e2;
    int lane = tid & 63, wid = tid >> 6;
    int v = a;
    for (int d = 1; d < 64; d <<= 1) {
        int t = __shfl_up(v, d);
        if (lane >= d) v += t;
    }
    if (lane == 63) ws[wid] = v;
    __syncthreads();
    int woff = 0;
    for (int w = 0; w < wid; ++w) woff += ws[w];
    int excl = woff + v - a;
    if (t0 < NBLK) base_all[b * NBLK + t0] = excl;              // coalesced
    if (t0 + 1 < NBLK) base_all[b * NBLK + t0 + 1] = excl + e0;
    if (t0 + 2 < NBLK) base_all[b * NBLK + t0 + 2] = excl + e0 + e1;
    if (tid == 511) totals[b] = woff + v;
}

// ---------------------------------------------------------------------------
// Phase 1d: LDS-sorted scatter, one 3072-item chunk per block.
// SINGLE LDS atomic per item; dest = slot + delta[b]. LDS ~33.4 KB.
// ---------------------------------------------------------------------------
__global__ void p1_scatter_kernel(const float* __restrict__ vals_up,
                                  const float* __restrict__ vals_pu,
                                  const int* __restrict__ rows_up,
                                  const int* __restrict__ rows_pu,
                                  const int* __restrict__ cols_up,
                                  const int* __restrict__ cols_pu,
                                  const int* __restrict__ base_all,
                                  unsigned* __restrict__ stag_pay,
                                  unsigned char* __restrict__ stag_row) {
    __shared__ unsigned spay[CHUNK];   // 12 KB payloads (slot order)
    __shared__ unsigned sdr[CHUNK];    // 12 KB: d<<7 | row_lo  (d < 2^22)
    __shared__ int h[NBK];             // 4.7 KB
    __shared__ int delta[NBK];         // 4.7 KB
    __shared__ int ws[4];

    int tid = threadIdx.x;
    int blk = blockIdx.x;
    for (int k = tid; k < NBK; k += 256) h[k] = 0;
    __syncthreads();

    int cbeg = blk * ITEMS;
    int cnt_items = NNZ2 - cbeg;
    if (cnt_items > CHUNK) cnt_items = CHUNK;

    unsigned rpay[CPT];
    int rrow[CPT];
    for (int k = 0; k < CPT; ++k) {
        int i = cbeg + k * 256 + tid;
        if (i < NNZ2) {
            int r, cc; float v;
            if (i < NNZ_C) { r = rows_up[i]; cc = cols_up[i]; v = vals_up[i]; }
            else { int q = i - NNZ_C; r = NU + rows_pu[q]; cc = cols_pu[q]; v = vals_pu[q]; }
            unsigned vb = __float_as_uint(v);
            unsigned vr = (vb + 0x7FFFu + ((vb >> 16) & 1u)) >> 16;  // bf16 bits
            rpay[k] = ((unsigned)cc << 15) | vr;
            rrow[k] = r;
            atomicAdd(&h[r >> RBSH], 1);
        } else {
            rrow[k] = -1;
        }
    }
    __syncthreads();

    {
        int s0 = tid * 5;                 // 256*5 = 1280 >= NBK
        int s1 = s0 + 5; if (s1 > NBK) s1 = NBK; if (s0 > NBK) s0 = NBK;
        int a = 0;
        for (int s = s0; s < s1; ++s) a += h[s];
        int lane = tid & 63, wid = tid >> 6;
        int v = a;
        for (int d = 1; d < 64; d <<= 1) {
            int t = __shfl_up(v, d);
            if (lane >= d) v += t;
        }
        if (lane == 63) ws[wid] = v;
        __syncthreads();
        int woff = 0;
        for (int w = 0; w < wid; ++w) woff += ws[w];
        int run = woff + v - a;
        for (int s = s0; s < s1; ++s) {
            int c = h[s];
            h[s] = run;
            delta[s] = bkt_base(s) + base_all[s * NBLK + blk] - run;
            run += c;
        }
    }
    __syncthreads();

    for (int k = 0; k < CPT; ++k) {
        if (rrow[k] < 0) continue;
        int b = rrow[k] >> RBSH;
        int slot = atomicAdd(&h[b], 1);
        int d = slot + delta[b];
        spay[slot] = rpay[k];
        sdr[slot] = ((unsigned)d << 7) | (unsigned)(rrow[k] & (RB - 1));
    }
    __syncthreads();

    for (int s = tid; s < cnt_items; s += 256) {
        unsigned q = sdr[s];
        int d = (int)(q >> 7);
        stag_pay[d] = spay[s];
        stag_row[d] = (unsigned char)(q & 127u);
    }
}

// ---------------------------------------------------------------------------
// finalize_up: buckets [0, 782) — single-pass register version (r14 style).
// These buckets feed gather-1, so they must complete before it launches.
// ---------------------------------------------------------------------------
__global__ void p2_finalize_up_kernel(const unsigned* __restrict__ stag_pay,
                                      const unsigned char* __restrict__ stag_row,
                                      const int* __restrict__ totals,
                                      unsigned* __restrict__ packed,
                                      int* __restrict__ row_beg,
                                      int* __restrict__ row_cnt) {
    __shared__ int cnt[RB];
    __shared__ int cur[RB];
    __shared__ int wtot;
    int b = blockIdx.x;                 // 0..781 (781 has CAP_PU window)
    int tid = threadIdx.x;
    int beg = bkt_base(b);
    int tot = totals[b];
    if (tid < RB) cnt[tid] = 0;
    __syncthreads();

    unsigned pay[FPT];
    unsigned char rw[FPT];
    #pragma unroll
    for (int k = 0; k < FPT; ++k) {
        int i = tid + k * 256;
        if (i < tot) {
            pay[k] = stag_pay[beg + i];
            rw[k] = stag_row[beg + i];
            atomicAdd(&cnt[rw[k]], 1);
        }
    }
    __syncthreads();

    int a = (tid < RB) ? cnt[tid] : 0;
    int lane = tid & 63;
    int v = a;
    for (int d = 1; d < 64; d <<= 1) {
        int t = __shfl_up(v, d);
        if (lane >= d) v += t;
    }
    if (tid == 63) wtot = v;
    __syncthreads();
    if (tid < RB) {
        int vv = (tid >= 64) ? v + wtot : v;
        int excl = vv - a;
        cur[tid] = beg + excl;
        int rr = (b << RBSH) + tid;
        if (rr < NR_TOT) { row_beg[rr] = beg + excl; row_cnt[rr] = a; }
    }
    __syncthreads();

    #pragma unroll
    for (int k = 0; k < FPT; ++k) {
        int i = tid + k * 256;
        if (i < tot) {
            int pos = atomicAdd(&cur[rw[k]], 1);
            packed[pos] = pay[k];
        }
    }
}

// ---------------------------------------------------------------------------
// Gather SpMM inner loop (unchanged, floored for 7 rounds).
// ---------------------------------------------------------------------------

#define NZ_FMA(P, U)                                            \
    do {                                                         \
        acc.x += dec_val(P) * __uint_as_float((U) << 16);        \
        acc.y += dec_val(P) * __uint_as_float((U) & 0xFFFF0000u);\
    } while (0)

__device__ inline void gather_row(const unsigned* __restrict__ packed,
                                  const unsigned* __restrict__ src,
                                  int beg, int end, int lane, float2& acc) {
    beg = __builtin_amdgcn_readfirstlane(beg);
    end = __builtin_amdgcn_readfirstlane(end);
    int n = end - beg;
    const unsigned* prow = packed + beg;
    int j = 0;
    for (; j + 8 <= n; j += 8) {
        unsigned p0 = prow[j + 0];
        unsigned p1 = prow[j + 1];
        unsigned p2 = prow[j + 2];
        unsigned p3 = prow[j + 3];
        unsigned p4 = prow[j + 4];
        unsigned p5 = prow[j + 5];
        unsigned p6 = prow[j + 6];
        unsigned p7 = prow[j + 7];
        unsigned u0 = src[(p0 >> 15) * 64 + lane];
        unsigned u1 = src[(p1 >> 15) * 64 + lane];
        unsigned u2 = src[(p2 >> 15) * 64 + lane];
        unsigned u3 = src[(p3 >> 15) * 64 + lane];
        unsigned u4 = src[(p4 >> 15) * 64 + lane];
        unsigned u5 = src[(p5 >> 15) * 64 + lane];
        unsigned u6 = src[(p6 >> 15) * 64 + lane];
        unsigned u7 = src[(p7 >> 15) * 64 + lane];
        NZ_FMA(p0, u0); NZ_FMA(p1, u1); NZ_FMA(p2, u2); NZ_FMA(p3, u3);
        NZ_FMA(p4, u4); NZ_FMA(p5, u5); NZ_FMA(p6, u6); NZ_FMA(p7, u7);
    }
    for (; j + 4 <= n; j += 4) {
        unsigned p0 = prow[j + 0];
        unsigned p1 = prow[j + 1];
        unsigned p2 = prow[j + 2];
        unsigned p3 = prow[j + 3];
        unsigned u0 = src[(p0 >> 15) * 64 + lane];
        unsigned u1 = src[(p1 >> 15) * 64 + lane];
        unsigned u2 = src[(p2 >> 15) * 64 + lane];
        unsigned u3 = src[(p3 >> 15) * 64 + lane];
        NZ_FMA(p0, u0); NZ_FMA(p1, u1); NZ_FMA(p2, u2); NZ_FMA(p3, u3);
    }
    for (; j < n; ++j) {
        unsigned p = prow[j];
        unsigned u = src[(p >> 15) * 64 + lane];
        NZ_FMA(p, u);
    }
}

// ---------------------------------------------------------------------------
// MERGED: gather-1 (up rows)  +  finalize of pu-only buckets [782, 1172).
// The two block families touch disjoint data: gather reads up-region
// packed/row_beg (written by finalize_up, previous launch); finalize-pu
// writes pu-region packed/row_beg (read only by gather-2, next launch).
// finalize-pu path is the two-pass LDS form -> low VGPR, preserves gather
// occupancy. Branch is block-uniform.
// ---------------------------------------------------------------------------
__global__ void spmm_gather1_finpu_kernel(int* __restrict__ row_beg,
                                          int* __restrict__ row_cnt,
                                          unsigned* __restrict__ packed,
                                          const unsigned* __restrict__ xh,
                                          unsigned* __restrict__ yh,
                                          const unsigned* __restrict__ stag_pay,
                                          const unsigned char* __restrict__ stag_row,
                                          const int* __restrict__ totals) {
    __shared__ int cnt[RB];
    __shared__ int cur[RB];
    __shared__ int wtot;
    if (blockIdx.x < G1_BLKS) {
        // gather-1: yh[r] = bf16(sum v * xh[c]) for up rows
        int r = blockIdx.x * 4 + (threadIdx.x >> 6);
        int lane = threadIdx.x & 63;
        int beg = row_beg[r], end = beg + row_cnt[r];
        float2 acc = make_float2(0.f, 0.f);
        gather_row(packed, xh, beg, end, lane, acc);
        yh[r * 64 + lane] = pack_bf16x2(acc.x, acc.y);
    } else {
        // finalize pu-only bucket (two-pass, LDS only)
        int b = FINUP_NB + (int)(blockIdx.x - G1_BLKS);   // 782..1171
        int tid = threadIdx.x;
        int beg = bkt_base(b), end = beg + totals[b];
        if (tid < RB) cnt[tid] = 0;
        __syncthreads();
        for (int i = beg + tid; i < end; i += 256)
            atomicAdd(&cnt[stag_row[i]], 1);
        __syncthreads();
        int a = (tid < RB) ? cnt[tid] : 0;
        int lane = tid & 63;
        int v = a;
        for (int d = 1; d < 64; d <<= 1) {
            int t = __shfl_up(v, d);
            if (lane >= d) v += t;
        }
        if (tid == 63) wtot = v;
        __syncthreads();
        if (tid < RB) {
            int vv = (tid >= 64) ? v + wtot : v;
            int excl = vv - a;
            cur[tid] = beg + excl;
            int rr = (b << RBSH) + tid;
            if (rr < NR_TOT) { row_beg[rr] = beg + excl; row_cnt[rr] = a; }
        }
        __syncthreads();
        for (int i = beg + tid; i < end; i += 256) {
            int pos = atomicAdd(&cur[stag_row[i]], 1);   // LDS only
            packed[pos] = stag_pay[i];
        }
    }
}

// Pass 2 fused: out[r] = sum v * yh[c] - x[r] + e[r]  (rows [NU,NU+NP))
__global__ void spmm_gather_fused_kernel(const int* __restrict__ row_beg,
                                         const int* __restrict__ row_cnt,
                                         const unsigned* __restrict__ packed,
                                         const unsigned* __restrict__ src, // yh
                                         const float* __restrict__ x,
                                         const float* __restrict__ e,
                                         float* __restrict__ out) {
    int r = blockIdx.x * 4 + (threadIdx.x >> 6);
    if (r >= NP) return;
    int lane = threadIdx.x & 63;
    int beg = row_beg[NU + r], end = beg + row_cnt[NU + r];
    float2 acc = make_float2(0.f, 0.f);
    gather_row(packed, src, beg, end, lane, acc);
    float2 xv = ((const float2*)(x + (size_t)r * DIM))[lane];
    float2 ev = ((const float2*)(e + (size_t)r * DIM))[lane];
    float2 o;
    o.x = acc.x - xv.x + ev.x;
    o.y = acc.y - xv.y + ev.y;
    ((float2*)(out + (size_t)r * DIM))[lane] = o;
}

extern "C" void kernel_launch(void* const* d_in, const int* in_sizes, int n_in,
                              void* d_out, int out_size, void* d_ws, size_t ws_size,
                              hipStream_t stream) {
    // setup_inputs order: t, x, e, vals_up, vals_pu, rows_up, cols_up, rows_pu, cols_pu
    const float* x       = (const float*)d_in[1];
    const float* e       = (const float*)d_in[2];
    const float* vals_up = (const float*)d_in[3];
    const float* vals_pu = (const float*)d_in[4];
    const int*   rows_up = (const int*)d_in[5];
    const int*   cols_up = (const int*)d_in[6];
    const int*   rows_pu = (const int*)d_in[7];
    const int*   cols_pu = (const int*)d_in[8];
    float* out = (float*)d_out;

    // Workspace layout (bytes), ~56.1 MB total:
    //   yh        : [0, 25,600,000)          NU*64 u32 (bf16x2)
    //     stag_pay aliases [0, 15,786,000)   NSLOT u32 (pu region stays live
    //                                        through gather-1's merged finalize;
    //                                        gather-1 writes yh[r*256B] only for
    //                                        up rows r<NU -> overlap with pu
    //                                        staging (beg >= bkt_base(782) =
    //                                        2,033,200 u32 = 8,132,800 B) is
    //                                        WRITTEN only after... NOTE: yh is
    //                                        25.6MB and stag_pay 15.8MB overlap
    //                                        fully -- but gather-1 blocks write
    //                                        yh while finalize-pu blocks READ
    //                                        stag_pay. See region check below.
    //   ...
    // CONFLICT CHECK: yh[0..25.6MB) vs stag_pay[0..15.8MB)+stag_row[16MB..20MB):
    // gather-1 writes yh words r*64+lane for r in [0,NU) -> bytes [0,25.6MB).
    // finalize-pu reads stag_pay bytes [8.13MB, 15.79MB) and stag_row bytes
    // [16MB+2.03MB, 16MB+3.95MB). stag_row region [18.03MB,19.95MB) does NOT
    // overlap yh writes?? yh extends to 25.6MB -> IT DOES. Therefore staging
    // must NOT alias yh when finalize-pu runs concurrently with gather-1.
    // FIX: move staging to its own region (no aliasing).
    //   yh        : [0, 25,600,000)
    //   xh        : [25,600,000, 38,400,000)
    //   packed    : [38,400,000, +15,786,000) = ends 54,186,000
    //     hist_all aliases [38,400,000, +4,884,896)   (dead before finalize)
    //     base_all aliases [43,284,896, +4,884,896)   (dead before finalize)
    //   stag_pay  : [54,186,000, +15,786,000) = ends 69,972,000
    //   stag_row  : [69,972,000, +3,946,500)  = ends 73,918,500
    //   totals    : [73,918,528, +4,688)
    //   row_beg   : [73,923,264, +600,000)
    //   row_cnt   : [74,523,264, +600,000)    = ends 75,123,264 (~75.1 MB)
    char* ws = (char*)d_ws;
    unsigned* yh     = (unsigned*)(ws);
    unsigned* xh     = (unsigned*)(ws + 25600000);
    unsigned* packed = (unsigned*)(ws + 38400000);
    int* hist_all    = (int*)(ws + 38400000);   // aliases packed (dead before finalize)
    int* base_all    = (int*)(ws + 43284896);   // aliases packed (dead before finalize)
    unsigned* stag_pay      = (unsigned*)(ws + 54186000);
    unsigned char* stag_row = (unsigned char*)(ws + 69972000);
    int* totals      = (int*)(ws + 73918528);
    int* row_beg     = (int*)(ws + 73923264);
    int* row_cnt     = (int*)(ws + 74523264);

    // Merged: x -> bf16  +  per-block bucket histogram (coalesced hist writes)
    cvt_hist_kernel<<<NBLK + CVT_BLKS, 256, 0, stream>>>(x, xh, rows_up,
                                                         rows_pu, hist_all);

    // Per-bucket scan of per-block counts
    p1_scan_kernel<<<NBK, 512, 0, stream>>>(hist_all, base_all, totals);
    p1_scatter_kernel<<<NBLK, 256, 0, stream>>>(vals_up, vals_pu,
                                                rows_up, rows_pu,
                                                cols_up, cols_pu,
                                                base_all,
                                                stag_pay, stag_row);

    // finalize of up buckets only (needed by gather-1)
    p2_finalize_up_kernel<<<FINUP_NB, 256, 0, stream>>>(stag_pay, stag_row,
                                                        totals, packed,
                                                        row_beg, row_cnt);

    // Pass 1 (up rows)  MERGED with  finalize of pu buckets
    spmm_gather1_finpu_kernel<<<G1_BLKS + FINPU_NB, 256, 0, stream>>>(
        row_beg, row_cnt, packed, xh, yh, stag_pay, stag_row, totals);

    // Pass 2: out = HG_pu @ yh - x + e
    spmm_gather_fused_kernel<<<(NP + 3) / 4, 256, 0, stream>>>(row_beg, row_cnt,
                                                               packed, yh,
                                                               x, e, out);
}